// Round 4
// baseline (3301.566 us; speedup 1.0000x reference)
//
#include <hip/hip_runtime.h>

// ---------------- problem constants ----------------
#define NDIST   45
#define NANG    7
#define NTOW    52          // 45 dist + 7 angle towers
#define NSLICE  128         // workgroups per tower -> grid 6656 = 13 exact rounds of 512 resident blocks
#define BF      64          // frames per frame-block
#define NIT     32          // frame-blocks per workgroup (262144/NSLICE/BF)
#define HSTRIDE 132         // f16 per LDS row: 264B (conflict-minimal, verified r3: 1.7e6)
#define BUFSZ   (BF * HSTRIDE)

typedef _Float16 f16;
typedef _Float16 f16x2 __attribute__((ext_vector_type(2)));
typedef _Float16 f16x4 __attribute__((ext_vector_type(4)));
typedef _Float16 f16x8 __attribute__((ext_vector_type(8)));
typedef float    f32x4 __attribute__((ext_vector_type(4)));

__device__ __forceinline__ f16x2 splat2(float v) { f16x2 r; r[0] = (f16)v; r[1] = (f16)v; return r; }
__device__ __forceinline__ f16x2 mk2(f16 a, f16 b) { f16x2 r; r[0] = a; r[1] = b; return r; }
__device__ __forceinline__ f16x2 pkrtz(float a, float b) {
  return __builtin_bit_cast(f16x2, __builtin_amdgcn_cvt_pkrtz(a, b));
}

// tanh(x) ~= xc * P(xc^2), xc = clamp(x, +-2.6); deg-4 Horner (verified r1-r3).
__device__ __forceinline__ f16x2 tanh_pk(f16x2 x) {
  x = __builtin_elementwise_max(x, splat2(-2.6f));
  x = __builtin_elementwise_min(x, splat2( 2.6f));
  f16x2 u = x * x;
  f16x2 p = u * splat2(0.00053778f) + splat2(-0.01005094f);
  p = u * p + splat2(0.07382459f);
  p = u * p + splat2(-0.29688618f);
  p = u * p + splat2(0.99552470f);
  return x * p;
}

// MFMA 16x16x32 f16 layout (verified rounds 1-3, absmax 0):
//   A-frag: lane l supplies A[m = l&15][k = 32*ks + 8*(l>>4) + j], j=0..7
//   B-frag: lane l supplies B[k = 32*ks + 8*(l>>4) + j][n = l&15]
//   D:      lane l, reg r holds D[m = 4*(l>>4) + r][n = l&15]
//
// Layer-split + quarter-split waves: wave w (role = w>>2) holds 32 rows
// [32*(w&3), 32*(w&3)+32) of its layer's W^T (areg[2][4] = 32 VGPR).
// Role 0 = gemm1, role 1 = gemm2. Each wave loops all 4 frame-strips.
// Biases ride in the MFMA C-operand (f32 regs); wo + layer-0 params live in
// registers for the whole kernel -> zero per-iter parameter LDS traffic.
// Budget ~110 regs < 128 -> 4 waves/SIMD with no spill.

__global__ __launch_bounds__(512, 4)
void towers_kernel(const float* __restrict__ F_dist, const float* __restrict__ F_cos,
                   const float* __restrict__ F_sin,
                   const float* __restrict__ Zd,  const float* __restrict__ Zc,
                   const float* __restrict__ Zs,  const float* __restrict__ BC,
                   const float* __restrict__ W1d, const float* __restrict__ b1d,
                   const float* __restrict__ Whd, const float* __restrict__ bhd,
                   const float* __restrict__ Wod, const float* __restrict__ bod,
                   const float* __restrict__ W1a, const float* __restrict__ b1a,
                   const float* __restrict__ Wha, const float* __restrict__ bha,
                   const float* __restrict__ Woa, const float* __restrict__ boa,
                   float* __restrict__ out)
{
  __shared__ __align__(16) f16 buf[4 * BUFSZ];     // H0 = buf[0,1], H1 = buf[2,3]; also W-stage scratch
  __shared__ __align__(16) f16 sW1x[128], sW1y[128], sB1[128];
  __shared__ float sScal[8];
  __shared__ float sRed[8];

  const int tid  = threadIdx.x;
  const int wid  = tid >> 6;
  const int lane = tid & 63;
  const int fl   = lane & 15;
  const int g    = lane >> 4;
  const int role = wid >> 2;       // 0: gemm1 waves, 1: gemm2 waves
  const int h2   = wid & 3;        // 32-row slice of W^T this wave owns
  const int T     = blockIdx.x / NSLICE;
  const int slice = blockIdx.x - T * NSLICE;
  const bool isDist = (T < NDIST);
  const int Ai = T - NDIST;

  // ---- stage layer-0 params to LDS (then hoisted into regs by every thread) ----
  if (tid < 128) {
    const int n = tid;
    float w1x, w1y, b1v;
    if (isDist) { w1x = W1d[T*128+n]; w1y = 0.f; b1v = b1d[T*128+n]; }
    else { w1x = W1a[(Ai*2+0)*128+n]; w1y = W1a[(Ai*2+1)*128+n]; b1v = b1a[Ai*128+n]; }
    sW1x[n] = (f16)w1x; sW1y[n] = (f16)w1y; sB1[n] = (f16)b1v;
  }
  if (tid == 0) {
    if (isDist) { sScal[0]=Zd[T]; sScal[1]=1.f/Zd[NDIST+T]; sScal[2]=0.f; sScal[3]=0.f; sScal[4]=bod[T]; }
    else { sScal[0]=Zc[0]; sScal[1]=1.f/Zc[NANG]; sScal[2]=Zs[0]; sScal[3]=1.f/Zs[NANG]; sScal[4]=boa[Ai]; }
  }

  // ---- per-wave register-resident params: bias (MFMA C-init) + wo ----
  const int rbo = 32*h2 + 4*g;     // D row base (+16*mt)
  const float* __restrict__ bhp = isDist ? (bhd + (size_t)(role*NDIST+T)*128)
                                         : (bha + (size_t)(role*NANG+Ai)*128);
  f32x4 bias[2];
  bias[0] = *(const f32x4*)&bhp[rbo];
  bias[1] = *(const f32x4*)&bhp[rbo + 16];
  f16x2 wlo[2], whi[2];
  if (role == 1) {
    const float* __restrict__ wop = isDist ? (Wod + (size_t)T*128) : (Woa + (size_t)Ai*128);
    #pragma unroll
    for (int mt = 0; mt < 2; ++mt) {
      const f32x4 w4 = *(const f32x4*)&wop[rbo + 16*mt];
      wlo[mt] = pkrtz(w4[0], w4[1]);
      whi[mt] = pkrtz(w4[2], w4[3]);
    }
  }

  // ---- stage Wt = W^T (f16) into buf; role-l waves grab their 32-row areg slice ----
  const float* __restrict__ WhB = isDist ? (Whd + (size_t)T*16384) : (Wha + (size_t)Ai*16384);
  const size_t Wls = isDist ? (size_t)NDIST*16384 : (size_t)NANG*16384;
  f16x8 areg[2][4];

  #pragma unroll 1
  for (int l = 0; l < 2; ++l) {
    const float* __restrict__ src = WhB + (size_t)l * Wls;
    const int m = tid & 127;
    #pragma unroll 4
    for (int p = 0; p < 16; ++p) {
      const int n = 2*((tid >> 7) + 4*p);
      f16x2 v; v[0] = (f16)src[(size_t)n*128 + m]; v[1] = (f16)src[(size_t)(n+1)*128 + m];
      *(f16x2*)&buf[m*HSTRIDE + n] = v;            // Wt[m][n] = Wh[n][m]
    }
    __syncthreads();
    if (role == l) {
      #pragma unroll
      for (int mt = 0; mt < 2; ++mt)
        #pragma unroll
        for (int ks = 0; ks < 4; ++ks)
          areg[mt][ks] = *(const f16x8*)&buf[(32*h2 + 16*mt + fl)*HSTRIDE + 32*ks + 8*g];
    }
    __syncthreads();
  }

  // ---- layer-0 params into registers (post-barrier, stay live all loop) ----
  const float zm0 = sScal[0], zsi0 = sScal[1], zm1 = sScal[2], zsi1 = sScal[3];
  const int fq = tid >> 4;                 // 0..31
  const int n0 = 8 * (tid & 15);
  const f16x8 w8 = *(const f16x8*)&sW1x[n0];
  const f16x8 b8 = *(const f16x8*)&sB1[n0];
  f16x8 w8y;
  if (!isDist) w8y = *(const f16x8*)&sW1y[n0];

  // bond/repel fold (each frame's x loaded by 16 threads -> scale 1/16)
  float bK = 0.f, bEq = 0.f;
  if (isDist && T < 9) { bK = 0.03125f * BC[T]; bEq = BC[16 + T]; }   // 0.5/16 * k
  const bool doRep = isDist && (T >= 17);

  // running input pointers (cuts per-iter 64-bit address math)
  const int colstride = isDist ? NDIST : NANG;
  const size_t f00 = (size_t)slice * (BF * NIT) + fq;
  const float* __restrict__ xp = isDist ? (F_dist + f00*NDIST + T) : (F_cos + f00*NANG);
  const float* __restrict__ yp = isDist ? nullptr : (F_sin + f00*NANG);
  const int xoff32 = 32 * colstride;
  const int xstep  = BF * colstride;

  float accY = 0.f;

  #pragma unroll 1
  for (int it = 0; it < NIT + 2; ++it) {
    // ---- issue x loads for fblock it (consumed by layer0 at iter end) ----
    float xra, xrb, yra, yrb;
    if (it < NIT) {
      xra = xp[0]; xrb = xp[xoff32];
      if (!isDist) { yra = yp[0]; yrb = yp[xoff32]; yp += xstep; }
      xp += xstep;
    }

    if (role == 0) {
      // ---- gemm1(it-1): H0[(it-1)&1] -> tanh -> H1[(it-1)&1] ----
      if (it >= 1 && it <= NIT) {
        const f16* __restrict__ Hr = buf + ((it-1) & 1) * BUFSZ;
        f16*       __restrict__ Hw = buf + (2 + ((it-1) & 1)) * BUFSZ;
        #pragma unroll 1
        for (int si = 0; si < 4; ++si) {
          const int row = 16*si + fl;
          const f16* __restrict__ hp = Hr + row*HSTRIDE + 8*g;
          const f16x8 b0 = *(const f16x8*)(hp);
          const f16x8 b1 = *(const f16x8*)(hp + 32);
          const f16x8 b2 = *(const f16x8*)(hp + 64);
          const f16x8 b3 = *(const f16x8*)(hp + 96);
          f32x4 a0 = bias[0], a1 = bias[1];
          __builtin_amdgcn_s_setprio(1);
          a0 = __builtin_amdgcn_mfma_f32_16x16x32_f16(areg[0][0], b0, a0, 0, 0, 0);
          a1 = __builtin_amdgcn_mfma_f32_16x16x32_f16(areg[1][0], b0, a1, 0, 0, 0);
          a0 = __builtin_amdgcn_mfma_f32_16x16x32_f16(areg[0][1], b1, a0, 0, 0, 0);
          a1 = __builtin_amdgcn_mfma_f32_16x16x32_f16(areg[1][1], b1, a1, 0, 0, 0);
          a0 = __builtin_amdgcn_mfma_f32_16x16x32_f16(areg[0][2], b2, a0, 0, 0, 0);
          a1 = __builtin_amdgcn_mfma_f32_16x16x32_f16(areg[1][2], b2, a1, 0, 0, 0);
          a0 = __builtin_amdgcn_mfma_f32_16x16x32_f16(areg[0][3], b3, a0, 0, 0, 0);
          a1 = __builtin_amdgcn_mfma_f32_16x16x32_f16(areg[1][3], b3, a1, 0, 0, 0);
          __builtin_amdgcn_s_setprio(0);
          f16* __restrict__ wp = Hw + row*HSTRIDE + rbo;
          {
            const f16x2 lo = tanh_pk(pkrtz(a0[0], a0[1]));
            const f16x2 hi = tanh_pk(pkrtz(a0[2], a0[3]));
            f16x4 o; o[0]=lo[0]; o[1]=lo[1]; o[2]=hi[0]; o[3]=hi[1];
            *(f16x4*)(wp) = o;
          }
          {
            const f16x2 lo = tanh_pk(pkrtz(a1[0], a1[1]));
            const f16x2 hi = tanh_pk(pkrtz(a1[2], a1[3]));
            f16x4 o; o[0]=lo[0]; o[1]=lo[1]; o[2]=hi[0]; o[3]=hi[1];
            *(f16x4*)(wp + 16) = o;
          }
        }
      }
    } else {
      // ---- gemm2(it-2): H1[(it-2)&1] -> tanh -> dot(wo) -> accY ----
      if (it >= 2) {
        const f16* __restrict__ Hr = buf + (2 + (it & 1)) * BUFSZ;
        #pragma unroll 1
        for (int si = 0; si < 4; ++si) {
          const int row = 16*si + fl;
          const f16* __restrict__ hp = Hr + row*HSTRIDE + 8*g;
          const f16x8 b0 = *(const f16x8*)(hp);
          const f16x8 b1 = *(const f16x8*)(hp + 32);
          const f16x8 b2 = *(const f16x8*)(hp + 64);
          const f16x8 b3 = *(const f16x8*)(hp + 96);
          f32x4 a0 = bias[0], a1 = bias[1];
          __builtin_amdgcn_s_setprio(1);
          a0 = __builtin_amdgcn_mfma_f32_16x16x32_f16(areg[0][0], b0, a0, 0, 0, 0);
          a1 = __builtin_amdgcn_mfma_f32_16x16x32_f16(areg[1][0], b0, a1, 0, 0, 0);
          a0 = __builtin_amdgcn_mfma_f32_16x16x32_f16(areg[0][1], b1, a0, 0, 0, 0);
          a1 = __builtin_amdgcn_mfma_f32_16x16x32_f16(areg[1][1], b1, a1, 0, 0, 0);
          a0 = __builtin_amdgcn_mfma_f32_16x16x32_f16(areg[0][2], b2, a0, 0, 0, 0);
          a1 = __builtin_amdgcn_mfma_f32_16x16x32_f16(areg[1][2], b2, a1, 0, 0, 0);
          a0 = __builtin_amdgcn_mfma_f32_16x16x32_f16(areg[0][3], b3, a0, 0, 0, 0);
          a1 = __builtin_amdgcn_mfma_f32_16x16x32_f16(areg[1][3], b3, a1, 0, 0, 0);
          __builtin_amdgcn_s_setprio(0);
          f16x2 y2;
          {
            const f16x2 lo = tanh_pk(pkrtz(a0[0], a0[1]));
            const f16x2 hi = tanh_pk(pkrtz(a0[2], a0[3]));
            y2 = lo * wlo[0];
            y2 = y2 + hi * whi[0];
          }
          {
            const f16x2 lo = tanh_pk(pkrtz(a1[0], a1[1]));
            const f16x2 hi = tanh_pk(pkrtz(a1[2], a1[3]));
            y2 = y2 + lo * wlo[1];
            y2 = y2 + hi * whi[1];
          }
          accY += (float)y2[0] + (float)y2[1];
        }
      }
    }

    // ---- layer0(it): x -> H0[it&1], all 8 waves; + folded bond/repel ----
    if (it < NIT) {
      f16* __restrict__ Hw = buf + (it & 1) * BUFSZ;
      #pragma unroll
      for (int p = 0; p < 2; ++p) {
        const float xraw = p ? xrb : xra;
        if (bK != 0.f) { const float t = xraw - bEq; accY += bK * t * t; }
        if (doRep) {
          const float v2 = xraw * xraw;
          const float v6 = v2 * v2 * v2;
          accY += 1730.0400390625f * __builtin_amdgcn_rcpf(v6);   // 5.5^6/16 / d^6
        }
        const float xs = (xraw - zm0) * zsi0;
        const f16x2 xn = pkrtz(xs, xs);
        f16x2 yn;
        if (!isDist) { const float ys = ((p ? yrb : yra) - zm1) * zsi1; yn = pkrtz(ys, ys); }
        f16x8 h8;
        #pragma unroll
        for (int q = 0; q < 4; ++q) {
          f16x2 a = mk2(w8[2*q], w8[2*q+1]) * xn + mk2(b8[2*q], b8[2*q+1]);
          if (!isDist) a = a + mk2(w8y[2*q], w8y[2*q+1]) * yn;
          const f16x2 t = tanh_pk(a);
          h8[2*q] = t[0]; h8[2*q+1] = t[1];
        }
        *(f16x8*)&Hw[(fq + 32*p)*HSTRIDE + n0] = h8;
      }
    }
    __syncthreads();
  }

  // ---- single reduction at the end ----
  #pragma unroll
  for (int off = 1; off < 64; off <<= 1) accY += __shfl_xor(accY, off, 64);
  if (lane == 0) sRed[wid] = accY;
  __syncthreads();
  if (tid == 0) {
    float tot = sRed[0]+sRed[1]+sRed[2]+sRed[3]+sRed[4]+sRed[5]+sRed[6]+sRed[7];
    tot += sScal[4] * (float)(BF * NIT);   // + bo per frame
    atomicAdd(out, tot);
  }
}

// ---------------- angle-only bond (F_dist terms folded into towers_kernel) ----------------
__global__ __launch_bounds__(256)
void angle_bond_kernel(const float* __restrict__ Fa, const float* __restrict__ BC,
                       float* __restrict__ out)
{
  __shared__ float sa[256 * NANG];
  __shared__ float sred[4];
  const int tid = threadIdx.x;
  const size_t b0 = (size_t)blockIdx.x * 256;
  for (int k = tid; k < 256 * NANG; k += 256) sa[k] = Fa[b0 * NANG + k];
  __syncthreads();
  const float* a = &sa[tid * NANG];
  float bond = 0.f;
  #pragma unroll
  for (int j = 0; j < 7; ++j) { float t = a[j] - BC[16 + 9 + j]; bond += BC[9 + j] * t * t; }
  float u = 0.5f * bond;
  #pragma unroll
  for (int off = 32; off >= 1; off >>= 1) u += __shfl_xor(u, off, 64);
  if ((tid & 63) == 0) sred[tid >> 6] = u;
  __syncthreads();
  if (tid == 0) atomicAdd(out, sred[0] + sred[1] + sred[2] + sred[3]);
}

extern "C" void kernel_launch(void* const* d_in, const int* in_sizes, int n_in,
                              void* d_out, int out_size, void* d_ws, size_t ws_size,
                              hipStream_t stream)
{
  (void)in_sizes; (void)n_in; (void)d_ws; (void)ws_size; (void)out_size;
  const float* F_dist  = (const float*)d_in[0];
  const float* F_cos   = (const float*)d_in[1];
  const float* F_sin   = (const float*)d_in[2];
  const float* F_angle = (const float*)d_in[3];
  const float* Zd      = (const float*)d_in[4];
  const float* Zc      = (const float*)d_in[5];
  const float* Zs      = (const float*)d_in[6];
  const float* BC      = (const float*)d_in[7];
  const float* W1d     = (const float*)d_in[8];
  const float* b1d     = (const float*)d_in[9];
  const float* Whd     = (const float*)d_in[10];
  const float* bhd     = (const float*)d_in[11];
  const float* Wod     = (const float*)d_in[12];
  const float* bod     = (const float*)d_in[13];
  const float* W1a     = (const float*)d_in[14];
  const float* b1a     = (const float*)d_in[15];
  const float* Wha     = (const float*)d_in[16];
  const float* bha     = (const float*)d_in[17];
  const float* Woa     = (const float*)d_in[18];
  const float* boa     = (const float*)d_in[19];
  float* out = (float*)d_out;

  hipMemsetAsync(d_out, 0, sizeof(float), stream);
  angle_bond_kernel<<<dim3(262144 / 256), dim3(256), 0, stream>>>(F_angle, BC, out);
  towers_kernel<<<dim3(NTOW * NSLICE), dim3(512), 0, stream>>>(
      F_dist, F_cos, F_sin, Zd, Zc, Zs, BC,
      W1d, b1d, Whd, bhd, Wod, bod,
      W1a, b1a, Wha, bha, Woa, boa, out);
}

// Round 5
// 2197.396 us; speedup vs baseline: 1.5025x; 1.5025x over previous
//
#include <hip/hip_runtime.h>

// ---------------- problem constants ----------------
#define NDIST   45
#define NANG    7
#define NTOW    52          // 45 dist + 7 angle towers
#define NSLICE  64          // workgroups per tower -> grid 3328 = 13 exact rounds, 1 block/CU
#define BF      128         // frames per frame-block
#define NFBLK   32          // frame-blocks per workgroup  (262144/NSLICE/BF)
#define HSTRIDE 132         // f16 per LDS row: 264B (conflict-minimal; r3/r4 evidence 1.7e6 vs 9e7 @136)

typedef _Float16 f16;
typedef _Float16 f16x2 __attribute__((ext_vector_type(2)));
typedef _Float16 f16x4 __attribute__((ext_vector_type(4)));
typedef _Float16 f16x8 __attribute__((ext_vector_type(8)));
typedef float    f32x4 __attribute__((ext_vector_type(4)));

__device__ __forceinline__ f16x2 splat2(float v) { f16x2 r; r[0] = (f16)v; r[1] = (f16)v; return r; }
__device__ __forceinline__ f16x2 mk2(f16 a, f16 b) { f16x2 r; r[0] = a; r[1] = b; return r; }
__device__ __forceinline__ f16x2 pkrtz(float a, float b) {
  return __builtin_bit_cast(f16x2, __builtin_amdgcn_cvt_pkrtz(a, b));
}

// tanh(x) ~= xc * P(xc^2), xc = clamp(x, +-2.6); deg-3 Horner in u=x^2 (7 pk ops).
// |err| ~0.03 incl. clamp tail -- budget is ~2.6e10, NN term ~1e5: free.
__device__ __forceinline__ f16x2 tanh_pk(f16x2 x) {
  x = __builtin_elementwise_max(x, splat2(-2.6f));
  x = __builtin_elementwise_min(x, splat2( 2.6f));
  f16x2 u = x * x;
  f16x2 p = u * splat2(-0.0033629f) + splat2(0.049105f);
  p = u * p + splat2(-0.27007f);
  p = u * p + splat2(0.99184f);
  return x * p;
}

// MFMA 16x16x32 f16 layout (verified rounds 1-4, absmax 0):
//   A-frag: lane l supplies A[m = l&15][k = 32*ks + 8*(l>>4) + j], j=0..7
//   B-frag: lane l supplies B[k = 32*ks + 8*(l>>4) + j][n = l&15]
//   D:      lane l, reg r holds D[m = 4*(l>>4) + r][n = l&15]
//
// r2 structure (best measured): half-split waves -- wave w holds rows
// [64*(w&1), +64) of BOTH layers' W^T (areg1+areg2 = 128 VGPR), wave pair
// (2s,2s+1) covers strips {s, s+4}. All 8 waves do identical per-iter work.
// New in r5: per-wave PHASE DESYNC (gemm order swapped by parity so the two
// waves sharing a SIMD stall at different points), deg-3 tanh, zscore folded
// into layer-0 weights, HSTRIDE 132.

__global__ __launch_bounds__(512, 2)
void towers_kernel(const float* __restrict__ F_dist, const float* __restrict__ F_cos,
                   const float* __restrict__ F_sin,
                   const float* __restrict__ Zd,  const float* __restrict__ Zc,
                   const float* __restrict__ Zs,  const float* __restrict__ BC,
                   const float* __restrict__ W1d, const float* __restrict__ b1d,
                   const float* __restrict__ Whd, const float* __restrict__ bhd,
                   const float* __restrict__ Wod, const float* __restrict__ bod,
                   const float* __restrict__ W1a, const float* __restrict__ b1a,
                   const float* __restrict__ Wha, const float* __restrict__ bha,
                   const float* __restrict__ Woa, const float* __restrict__ boa,
                   float* __restrict__ out)
{
  __shared__ __align__(16) f16 H0[2][BF * HSTRIDE];   // layer-0 activations (double buffer)
  __shared__ __align__(16) f16 H1[2][BF * HSTRIDE];   // layer-1 activations ([0] also W-stage scratch)
  __shared__ __align__(16) f16 sW1x[128], sW1y[128], sB1[128];
  __shared__ float sScal[8];
  __shared__ float sRed[8];

  const int tid  = threadIdx.x;
  const int wid  = tid >> 6;
  const int lane = tid & 63;
  const int fl   = lane & 15;
  const int g    = lane >> 4;
  const int h    = wid & 1;        // which 64-row half of W this wave owns
  const int ps   = wid >> 1;       // strip pair id: strips {ps, ps+4}
  const int par  = (wid ^ (wid >> 2)) & 1;  // phase-desync parity (robust to wave->SIMD pairing)
  const int T     = blockIdx.x / NSLICE;
  const int slice = blockIdx.x - T * NSLICE;
  const bool isDist = (T < NDIST);
  const int Ai = T - NDIST;

  // ---- stage layer-0 params with Zscore folded in: a = w1x'*x + w1y'*y + b1' ----
  if (tid < 128) {
    const int n = tid;
    float w1x, w1y, b1v, zm0, zs0i, zm1, zs1i;
    if (isDist) {
      w1x = W1d[T*128+n]; w1y = 0.f; b1v = b1d[T*128+n];
      zm0 = Zd[T]; zs0i = 1.f / Zd[NDIST+T]; zm1 = 0.f; zs1i = 0.f;
    } else {
      w1x = W1a[(Ai*2+0)*128+n]; w1y = W1a[(Ai*2+1)*128+n]; b1v = b1a[Ai*128+n];
      zm0 = Zc[0]; zs0i = 1.f / Zc[NANG]; zm1 = Zs[0]; zs1i = 1.f / Zs[NANG];
    }
    const float wx = w1x * zs0i, wy = w1y * zs1i;
    sW1x[n] = (f16)wx; sW1y[n] = (f16)wy;
    sB1[n]  = (f16)(b1v - wx * zm0 - wy * zm1);
  }
  if (tid == 0) sScal[4] = isDist ? bod[T] : boa[Ai];

  // ---- per-wave register params: biases as MFMA C-init, wo as pk f16 ----
  const int rb = 64*h + 4*g;       // D row base (+16*mt+r)
  const float* __restrict__ bh0p = isDist ? (bhd + (size_t)(0*NDIST+T)*128) : (bha + (size_t)(0*NANG+Ai)*128);
  const float* __restrict__ bh1p = isDist ? (bhd + (size_t)(1*NDIST+T)*128) : (bha + (size_t)(1*NANG+Ai)*128);
  const float* __restrict__ wop  = isDist ? (Wod + (size_t)T*128) : (Woa + (size_t)Ai*128);
  f32x4 bias1[4], bias2[4];
  f16x2 wlo[4], whi[4];
  #pragma unroll
  for (int mt = 0; mt < 4; ++mt) {
    bias1[mt] = *(const f32x4*)&bh0p[rb + 16*mt];
    bias2[mt] = *(const f32x4*)&bh1p[rb + 16*mt];
    const f32x4 w4 = *(const f32x4*)&wop[rb + 16*mt];
    wlo[mt] = pkrtz(w4[0], w4[1]);
    whi[mt] = pkrtz(w4[2], w4[3]);
  }

  // ---- stage Wt = W^T (f16) per layer into H1[0]; every wave grabs its 64-row half ----
  const float* __restrict__ WhB = isDist ? (Whd + (size_t)T*16384) : (Wha + (size_t)Ai*16384);
  const size_t Wls = isDist ? (size_t)NDIST*16384 : (size_t)NANG*16384;
  f16x8 areg1[4][4], areg2[4][4];

  auto stageW = [&](const float* __restrict__ src) {
    const int m = tid & 127;
    #pragma unroll 4
    for (int p = 0; p < 16; ++p) {
      const int n = 2*((tid >> 7) + 4*p);
      f16x2 v; v[0] = (f16)src[(size_t)n*128 + m]; v[1] = (f16)src[(size_t)(n+1)*128 + m];
      *(f16x2*)&H1[0][m*HSTRIDE + n] = v;              // Wt[m][n]
    }
  };
  stageW(WhB);
  __syncthreads();
  #pragma unroll
  for (int mt = 0; mt < 4; ++mt)
    #pragma unroll
    for (int ks = 0; ks < 4; ++ks)
      areg1[mt][ks] = *(const f16x8*)&H1[0][(64*h + 16*mt + fl)*HSTRIDE + 32*ks + 8*g];
  __syncthreads();
  stageW(WhB + Wls);
  __syncthreads();
  #pragma unroll
  for (int mt = 0; mt < 4; ++mt)
    #pragma unroll
    for (int ks = 0; ks < 4; ++ks)
      areg2[mt][ks] = *(const f16x8*)&H1[0][(64*h + 16*mt + fl)*HSTRIDE + 32*ks + 8*g];
  __syncthreads();

  const int n0 = 8*(tid & 15);
  const int fq = tid >> 4;                 // 0..31
  const f16x8 w8  = *(const f16x8*)&sW1x[n0];
  const f16x8 b8  = *(const f16x8*)&sB1[n0];
  f16x8 w8y;
  if (!isDist) w8y = *(const f16x8*)&sW1y[n0];

  // bond/repel fold (each frame's x loaded by 16 threads -> scale 1/16)
  float bK = 0.f, bEq = 0.f;
  if (isDist && T < 9) { bK = 0.03125f * BC[T]; bEq = BC[16 + T]; }   // 0.5/16 * k
  const bool doRep = isDist && (T >= 17);

  // running input pointers
  const int cs = isDist ? NDIST : NANG;
  const size_t f00 = (size_t)slice * (BF * NFBLK) + fq;
  const float* __restrict__ xp = isDist ? (F_dist + f00*NDIST + T) : (F_cos + f00*NANG);
  const float* __restrict__ yp = isDist ? nullptr : (F_sin + f00*NANG);
  const int xstep = BF * cs;

  float accY = 0.f;

  // ---- 3-stage pipeline, 1 barrier per 128-frame block; phase order desynced by parity ----
  #pragma unroll 1
  for (int it = 0; it < NFBLK + 2; ++it) {
    // issue layer-0 input loads early (hidden under the GEMMs)
    float xr0[4], xr1[4];
    if (it < NFBLK) {
      #pragma unroll
      for (int p = 0; p < 4; ++p) {
        xr0[p] = xp[32*p*cs];
        if (!isDist) xr1[p] = yp[32*p*cs];
      }
      xp += xstep;
      if (!isDist) yp += xstep;
    }

    auto do_gemm2 = [&]() {   // gemm2(it-2): H1[it&1] -> tanh -> dot(wo) -> accY
      if (it < 2) return;
      const f16* __restrict__ Hr = H1[it & 1];
      #pragma unroll
      for (int si = 0; si < 2; ++si) {
        const int fr = 16*(ps + 4*si) + fl;
        const f16* __restrict__ hp = Hr + fr*HSTRIDE + 8*g;
        f16x8 breg[4];
        #pragma unroll
        for (int ks = 0; ks < 4; ++ks) breg[ks] = *(const f16x8*)(hp + 32*ks);
        f16x2 y2 = splat2(0.f);
        #pragma unroll
        for (int mt = 0; mt < 4; ++mt) {
          f32x4 acc = bias2[mt];
          #pragma unroll
          for (int ks = 0; ks < 4; ++ks)
            acc = __builtin_amdgcn_mfma_f32_16x16x32_f16(areg2[mt][ks], breg[ks], acc, 0, 0, 0);
          f16x2 lo = tanh_pk(pkrtz(acc[0], acc[1]));
          f16x2 hi = tanh_pk(pkrtz(acc[2], acc[3]));
          y2 = y2 + lo * wlo[mt];
          y2 = y2 + hi * whi[mt];
        }
        accY += (float)y2[0] + (float)y2[1];
      }
    };

    auto do_gemm1 = [&]() {   // gemm1(it-1): H0[(it-1)&1] -> tanh -> H1[(it-1)&1]
      if (it < 1 || it > NFBLK) return;
      const f16* __restrict__ Hr = H0[(it-1) & 1];
      f16*       __restrict__ Hw = H1[(it-1) & 1];
      #pragma unroll
      for (int si = 0; si < 2; ++si) {
        const int fr = 16*(ps + 4*si) + fl;
        const f16* __restrict__ hp = Hr + fr*HSTRIDE + 8*g;
        f16x8 breg[4];
        #pragma unroll
        for (int ks = 0; ks < 4; ++ks) breg[ks] = *(const f16x8*)(hp + 32*ks);
        f16* __restrict__ wp = Hw + fr*HSTRIDE + rb;
        #pragma unroll
        for (int mt = 0; mt < 4; ++mt) {
          f32x4 acc = bias1[mt];
          #pragma unroll
          for (int ks = 0; ks < 4; ++ks)
            acc = __builtin_amdgcn_mfma_f32_16x16x32_f16(areg1[mt][ks], breg[ks], acc, 0, 0, 0);
          f16x2 lo = tanh_pk(pkrtz(acc[0], acc[1]));
          f16x2 hi = tanh_pk(pkrtz(acc[2], acc[3]));
          f16x4 o; o[0] = lo[0]; o[1] = lo[1]; o[2] = hi[0]; o[3] = hi[1];
          *(f16x4*)(wp + 16*mt) = o;                    // H1[frame][m_out]
        }
      }
    };

    if (par) { do_gemm1(); do_gemm2(); }
    else     { do_gemm2(); do_gemm1(); }

    // layer0(it): x -> H0[it&1]; + folded bond/repel on raw x
    if (it < NFBLK) {
      f16* __restrict__ Hw = H0[it & 1];
      #pragma unroll
      for (int p = 0; p < 4; ++p) {
        const float xraw = xr0[p];
        if (bK != 0.f) { const float t = xraw - bEq; accY += bK * t * t; }
        if (doRep) {
          const float v2 = xraw * xraw;
          const float v6 = v2 * v2 * v2;
          accY += 1730.0400390625f * __builtin_amdgcn_rcpf(v6);   // 5.5^6/16 / d^6
        }
        const f16x2 xn = pkrtz(xraw, xraw);
        f16x2 yn;
        if (!isDist) yn = pkrtz(xr1[p], xr1[p]);
        f16x8 h8;
        #pragma unroll
        for (int q = 0; q < 4; ++q) {
          f16x2 a = mk2(w8[2*q], w8[2*q+1]) * xn + mk2(b8[2*q], b8[2*q+1]);
          if (!isDist) a = a + mk2(w8y[2*q], w8y[2*q+1]) * yn;
          const f16x2 t = tanh_pk(a);
          h8[2*q] = t[0]; h8[2*q+1] = t[1];
        }
        *(f16x8*)&Hw[(fq + 32*p)*HSTRIDE + n0] = h8;
      }
    }
    __syncthreads();
  }

  // ---- single reduction at the end ----
  #pragma unroll
  for (int off = 1; off < 64; off <<= 1) accY += __shfl_xor(accY, off, 64);
  if (lane == 0) sRed[wid] = accY;
  __syncthreads();
  if (tid == 0) {
    float tot = sRed[0]+sRed[1]+sRed[2]+sRed[3]+sRed[4]+sRed[5]+sRed[6]+sRed[7];
    tot += sScal[4] * (float)(BF * NFBLK);   // + bo per frame
    atomicAdd(out, tot);
  }
}

// ---------------- angle-only bond (F_dist terms folded into towers_kernel) ----------------
__global__ __launch_bounds__(256)
void angle_bond_kernel(const float* __restrict__ Fa, const float* __restrict__ BC,
                       float* __restrict__ out)
{
  __shared__ float sa[256 * NANG];
  __shared__ float sred[4];
  const int tid = threadIdx.x;
  const size_t b0 = (size_t)blockIdx.x * 256;
  for (int k = tid; k < 256 * NANG; k += 256) sa[k] = Fa[b0 * NANG + k];
  __syncthreads();
  const float* a = &sa[tid * NANG];
  float bond = 0.f;
  #pragma unroll
  for (int j = 0; j < 7; ++j) { float t = a[j] - BC[16 + 9 + j]; bond += BC[9 + j] * t * t; }
  float u = 0.5f * bond;
  #pragma unroll
  for (int off = 32; off >= 1; off >>= 1) u += __shfl_xor(u, off, 64);
  if ((tid & 63) == 0) sred[tid >> 6] = u;
  __syncthreads();
  if (tid == 0) atomicAdd(out, sred[0] + sred[1] + sred[2] + sred[3]);
}

extern "C" void kernel_launch(void* const* d_in, const int* in_sizes, int n_in,
                              void* d_out, int out_size, void* d_ws, size_t ws_size,
                              hipStream_t stream)
{
  (void)in_sizes; (void)n_in; (void)d_ws; (void)ws_size; (void)out_size;
  const float* F_dist  = (const float*)d_in[0];
  const float* F_cos   = (const float*)d_in[1];
  const float* F_sin   = (const float*)d_in[2];
  const float* F_angle = (const float*)d_in[3];
  const float* Zd      = (const float*)d_in[4];
  const float* Zc      = (const float*)d_in[5];
  const float* Zs      = (const float*)d_in[6];
  const float* BC      = (const float*)d_in[7];
  const float* W1d     = (const float*)d_in[8];
  const float* b1d     = (const float*)d_in[9];
  const float* Whd     = (const float*)d_in[10];
  const float* bhd     = (const float*)d_in[11];
  const float* Wod     = (const float*)d_in[12];
  const float* bod     = (const float*)d_in[13];
  const float* W1a     = (const float*)d_in[14];
  const float* b1a     = (const float*)d_in[15];
  const float* Wha     = (const float*)d_in[16];
  const float* bha     = (const float*)d_in[17];
  const float* Woa     = (const float*)d_in[18];
  const float* boa     = (const float*)d_in[19];
  float* out = (float*)d_out;

  hipMemsetAsync(d_out, 0, sizeof(float), stream);
  angle_bond_kernel<<<dim3(262144 / 256), dim3(256), 0, stream>>>(F_angle, BC, out);
  towers_kernel<<<dim3(NTOW * NSLICE), dim3(512), 0, stream>>>(
      F_dist, F_cos, F_sin, Zd, Zc, Zs, BC,
      W1d, b1d, Whd, bhd, Wod, bod,
      W1a, b1a, Wha, bha, Woa, boa, out);
}

// Round 6
// 1540.636 us; speedup vs baseline: 2.1430x; 1.4263x over previous
//
#include <hip/hip_runtime.h>

// ---------------- problem constants ----------------
#define NDIST   45
#define NANG    7
#define NTOW    52          // 45 dist + 7 angle towers
#define NSLICE  64          // workgroups per tower -> grid 3328 = 13 exact rounds, 1 block/CU
#define BF      128         // frames per frame-block
#define NFBLK   32          // frame-blocks per workgroup  (262144/NSLICE/BF)
#define HSTRIDE 128         // f16 per row; 256B stride, XOR-swizzled (see swz) -> aligned + conflict-free

typedef _Float16 f16;
typedef _Float16 f16x2 __attribute__((ext_vector_type(2)));
typedef _Float16 f16x4 __attribute__((ext_vector_type(4)));
typedef _Float16 f16x8 __attribute__((ext_vector_type(8)));
typedef float    f32x4 __attribute__((ext_vector_type(4)));

// Swizzled LDS element offset: row stride 256B; XOR row bits into byte bits 4-6.
// Keeps 16B/8B/4B accesses intact (only block index flips) and spreads the
// 16 fl-lanes of a b128 read across all 8 bank-quads (8 lanes/quad = minimum).
__device__ __forceinline__ int swz(int row, int ec) {
  return row * HSTRIDE + (ec ^ ((row & 7) << 3));
}

__device__ __forceinline__ f16x2 splat2(float v) { f16x2 r; r[0] = (f16)v; r[1] = (f16)v; return r; }
__device__ __forceinline__ f16x2 mk2(f16 a, f16 b) { f16x2 r; r[0] = a; r[1] = b; return r; }
__device__ __forceinline__ f16x2 pkrtz(float a, float b) {
  return __builtin_bit_cast(f16x2, __builtin_amdgcn_cvt_pkrtz(a, b));
}

// tanh(x) ~= xc * P(xc^2), xc = clamp(x, +-2.6); deg-3 Horner (7 pk ops).
// |err| ~0.03 incl. clamp tail -- threshold 2.6e10, NN term ~1e5: free.
__device__ __forceinline__ f16x2 tanh_pk(f16x2 x) {
  x = __builtin_elementwise_max(x, splat2(-2.6f));
  x = __builtin_elementwise_min(x, splat2( 2.6f));
  f16x2 u = x * x;
  f16x2 p = u * splat2(-0.0033629f) + splat2(0.049105f);
  p = u * p + splat2(-0.27007f);
  p = u * p + splat2(0.99184f);
  return x * p;
}

// MFMA 16x16x32 f16 layout (verified rounds 1-5, absmax 0):
//   A-frag: lane l supplies A[m = l&15][k = 32*ks + 8*(l>>4) + j], j=0..7
//   B-frag: lane l supplies B[k = 32*ks + 8*(l>>4) + j][n = l&15]
//   D:      lane l, reg r holds D[m = 4*(l>>4) + r][n = l&15]
//
// r2 structure (best measured 1589us): half-split waves -- wave w holds rows
// [64*(w&1), +64) of BOTH layers' W^T (areg1+areg2), wave pair (2s,2s+1)
// covers strips {s, s+4}; all 8 waves do identical per-iter work; biases in
// MFMA C-init; wo + layer-0 params register-resident; 1 barrier/iter.

__global__ __launch_bounds__(512, 2)
void towers_kernel(const float* __restrict__ F_dist, const float* __restrict__ F_cos,
                   const float* __restrict__ F_sin,
                   const float* __restrict__ Zd,  const float* __restrict__ Zc,
                   const float* __restrict__ Zs,  const float* __restrict__ BC,
                   const float* __restrict__ W1d, const float* __restrict__ b1d,
                   const float* __restrict__ Whd, const float* __restrict__ bhd,
                   const float* __restrict__ Wod, const float* __restrict__ bod,
                   const float* __restrict__ W1a, const float* __restrict__ b1a,
                   const float* __restrict__ Wha, const float* __restrict__ bha,
                   const float* __restrict__ Woa, const float* __restrict__ boa,
                   float* __restrict__ out)
{
  __shared__ __align__(16) f16 H0[2][BF * HSTRIDE];   // layer-0 activations (double buffer)
  __shared__ __align__(16) f16 H1[2][BF * HSTRIDE];   // layer-1 activations ([0] also W-stage scratch)
  __shared__ __align__(16) f16 sW1x[128], sW1y[128], sB1[128];
  __shared__ float sScal[8];
  __shared__ float sRed[8];

  const int tid  = threadIdx.x;
  const int wid  = tid >> 6;
  const int lane = tid & 63;
  const int fl   = lane & 15;
  const int g    = lane >> 4;
  const int h    = wid & 1;        // which 64-row half of W this wave owns
  const int ps   = wid >> 1;       // strip pair id: strips {ps, ps+4}
  const int T     = blockIdx.x / NSLICE;
  const int slice = blockIdx.x - T * NSLICE;
  const bool isDist = (T < NDIST);
  const int Ai = T - NDIST;

  // ---- stage layer-0 params with Zscore folded in: a = wx*x + wy*y + b' ----
  if (tid < 128) {
    const int n = tid;
    float w1x, w1y, b1v, zm0, zs0i, zm1, zs1i;
    if (isDist) {
      w1x = W1d[T*128+n]; w1y = 0.f; b1v = b1d[T*128+n];
      zm0 = Zd[T]; zs0i = 1.f / Zd[NDIST+T]; zm1 = 0.f; zs1i = 0.f;
    } else {
      w1x = W1a[(Ai*2+0)*128+n]; w1y = W1a[(Ai*2+1)*128+n]; b1v = b1a[Ai*128+n];
      zm0 = Zc[0]; zs0i = 1.f / Zc[NANG]; zm1 = Zs[0]; zs1i = 1.f / Zs[NANG];
    }
    const float wx = w1x * zs0i, wy = w1y * zs1i;
    sW1x[n] = (f16)wx; sW1y[n] = (f16)wy;
    sB1[n]  = (f16)(b1v - wx * zm0 - wy * zm1);
  }
  if (tid == 0) sScal[4] = isDist ? bod[T] : boa[Ai];

  // ---- per-wave register params: biases as MFMA C-init, wo as pk f16 ----
  const int rb = 64*h + 4*g;       // D row base (+16*mt+r)
  const float* __restrict__ bh0p = isDist ? (bhd + (size_t)(0*NDIST+T)*128) : (bha + (size_t)(0*NANG+Ai)*128);
  const float* __restrict__ bh1p = isDist ? (bhd + (size_t)(1*NDIST+T)*128) : (bha + (size_t)(1*NANG+Ai)*128);
  const float* __restrict__ wop  = isDist ? (Wod + (size_t)T*128) : (Woa + (size_t)Ai*128);
  f32x4 bias1[4], bias2[4];
  f16x2 wlo[4], whi[4];
  #pragma unroll
  for (int mt = 0; mt < 4; ++mt) {
    bias1[mt] = *(const f32x4*)&bh0p[rb + 16*mt];
    bias2[mt] = *(const f32x4*)&bh1p[rb + 16*mt];
    const f32x4 w4 = *(const f32x4*)&wop[rb + 16*mt];
    wlo[mt] = pkrtz(w4[0], w4[1]);
    whi[mt] = pkrtz(w4[2], w4[3]);
  }

  // ---- stage Wt = W^T (f16) per layer into H1[0]; every wave grabs its 64-row half ----
  const float* __restrict__ WhB = isDist ? (Whd + (size_t)T*16384) : (Wha + (size_t)Ai*16384);
  const size_t Wls = isDist ? (size_t)NDIST*16384 : (size_t)NANG*16384;
  f16x8 areg1[4][4], areg2[4][4];

  auto stageW = [&](const float* __restrict__ src) {
    const int m = tid & 127;
    #pragma unroll 4
    for (int p = 0; p < 16; ++p) {
      const int n = 2*((tid >> 7) + 4*p);
      f16x2 v; v[0] = (f16)src[(size_t)n*128 + m]; v[1] = (f16)src[(size_t)(n+1)*128 + m];
      *(f16x2*)&H1[0][swz(m, n)] = v;                  // Wt[m][n]
    }
  };
  stageW(WhB);
  __syncthreads();
  #pragma unroll
  for (int mt = 0; mt < 4; ++mt) {
    const int row = 64*h + 16*mt + fl;
    #pragma unroll
    for (int ks = 0; ks < 4; ++ks)
      areg1[mt][ks] = *(const f16x8*)&H1[0][swz(row, 32*ks + 8*g)];
  }
  __syncthreads();
  stageW(WhB + Wls);
  __syncthreads();
  #pragma unroll
  for (int mt = 0; mt < 4; ++mt) {
    const int row = 64*h + 16*mt + fl;
    #pragma unroll
    for (int ks = 0; ks < 4; ++ks)
      areg2[mt][ks] = *(const f16x8*)&H1[0][swz(row, 32*ks + 8*g)];
  }
  __syncthreads();

  const int n0 = 8*(tid & 15);
  const int fq = tid >> 4;                 // 0..31
  const f16x8 w8  = *(const f16x8*)&sW1x[n0];
  const f16x8 b8  = *(const f16x8*)&sB1[n0];
  f16x8 w8y;
  if (!isDist) w8y = *(const f16x8*)&sW1y[n0];

  // bond/repel fold (each frame's x loaded by 16 threads -> scale 1/16)
  float bK = 0.f, bEq = 0.f;
  if (isDist && T < 9) { bK = 0.03125f * BC[T]; bEq = BC[16 + T]; }   // 0.5/16 * k
  const bool doRep = isDist && (T >= 17);

  float accY = 0.f;
  const int fb0 = slice * NFBLK;

  // ---- 3-stage pipeline, 1 barrier per 128-frame block (r2 order: loads, gemm2, gemm1, layer0) ----
  #pragma unroll 1
  for (int it = 0; it < NFBLK + 2; ++it) {
    // issue layer-0 input loads early (hidden under the GEMMs)
    float xr0[4], xr1[4];
    if (it < NFBLK) {
      const size_t frame0 = (size_t)(fb0 + it) * BF;
      #pragma unroll
      for (int p = 0; p < 4; ++p) {
        const size_t gf = frame0 + fq + 32*p;
        if (isDist) { xr0[p] = F_dist[gf*NDIST + T]; xr1[p] = 0.f; }
        else        { xr0[p] = F_cos[gf*NANG];       xr1[p] = F_sin[gf*NANG]; }
      }
    }
    // gemm2(it-2): H1[(it-2)&1] -> tanh -> dot(wo) -> accY
    if (it >= 2) {
      const f16* __restrict__ Hr = H1[it & 1];
      #pragma unroll
      for (int si = 0; si < 2; ++si) {
        const int fr = 16*(ps + 4*si) + fl;
        f16x8 breg[4];
        #pragma unroll
        for (int ks = 0; ks < 4; ++ks) breg[ks] = *(const f16x8*)&Hr[swz(fr, 32*ks + 8*g)];
        f16x2 y2 = splat2(0.f);
        #pragma unroll
        for (int mt = 0; mt < 4; ++mt) {
          f32x4 acc = bias2[mt];
          #pragma unroll
          for (int ks = 0; ks < 4; ++ks)
            acc = __builtin_amdgcn_mfma_f32_16x16x32_f16(areg2[mt][ks], breg[ks], acc, 0, 0, 0);
          f16x2 lo = tanh_pk(pkrtz(acc[0], acc[1]));
          f16x2 hi = tanh_pk(pkrtz(acc[2], acc[3]));
          y2 = y2 + lo * wlo[mt];
          y2 = y2 + hi * whi[mt];
        }
        accY += (float)y2[0] + (float)y2[1];
      }
    }
    // gemm1(it-1): H0[(it-1)&1] -> tanh -> H1[(it-1)&1]
    if (it >= 1 && it <= NFBLK) {
      const f16* __restrict__ Hr = H0[(it-1) & 1];
      f16*       __restrict__ Hw = H1[(it-1) & 1];
      #pragma unroll
      for (int si = 0; si < 2; ++si) {
        const int fr = 16*(ps + 4*si) + fl;
        f16x8 breg[4];
        #pragma unroll
        for (int ks = 0; ks < 4; ++ks) breg[ks] = *(const f16x8*)&Hr[swz(fr, 32*ks + 8*g)];
        #pragma unroll
        for (int mt = 0; mt < 4; ++mt) {
          f32x4 acc = bias1[mt];
          #pragma unroll
          for (int ks = 0; ks < 4; ++ks)
            acc = __builtin_amdgcn_mfma_f32_16x16x32_f16(areg1[mt][ks], breg[ks], acc, 0, 0, 0);
          f16x2 lo = tanh_pk(pkrtz(acc[0], acc[1]));
          f16x2 hi = tanh_pk(pkrtz(acc[2], acc[3]));
          f16x4 o; o[0] = lo[0]; o[1] = lo[1]; o[2] = hi[0]; o[3] = hi[1];
          *(f16x4*)&Hw[swz(fr, rb + 16*mt)] = o;        // H1[frame][m_out]
        }
      }
    }
    // layer0(it): x -> H0[it&1]; + folded bond/repel on raw x
    if (it < NFBLK) {
      f16* __restrict__ Hw = H0[it & 1];
      #pragma unroll
      for (int p = 0; p < 4; ++p) {
        const float xraw = xr0[p];
        if (bK != 0.f) { const float t = xraw - bEq; accY += bK * t * t; }
        if (doRep) {
          const float v2 = xraw * xraw;
          const float v6 = v2 * v2 * v2;
          accY += 1730.0400390625f * __builtin_amdgcn_rcpf(v6);   // 5.5^6/16 / d^6
        }
        const f16x2 xn = pkrtz(xraw, xraw);
        f16x2 yn;
        if (!isDist) yn = pkrtz(xr1[p], xr1[p]);
        f16x8 h8;
        #pragma unroll
        for (int q = 0; q < 4; ++q) {
          f16x2 a = mk2(w8[2*q], w8[2*q+1]) * xn + mk2(b8[2*q], b8[2*q+1]);
          if (!isDist) a = a + mk2(w8y[2*q], w8y[2*q+1]) * yn;
          const f16x2 t = tanh_pk(a);
          h8[2*q] = t[0]; h8[2*q+1] = t[1];
        }
        *(f16x8*)&Hw[swz(fq + 32*p, n0)] = h8;
      }
    }
    __syncthreads();
  }

  // ---- single reduction at the end ----
  #pragma unroll
  for (int off = 1; off < 64; off <<= 1) accY += __shfl_xor(accY, off, 64);
  if (lane == 0) sRed[wid] = accY;
  __syncthreads();
  if (tid == 0) {
    float tot = sRed[0]+sRed[1]+sRed[2]+sRed[3]+sRed[4]+sRed[5]+sRed[6]+sRed[7];
    tot += sScal[4] * (float)(BF * NFBLK);   // + bo per frame
    atomicAdd(out, tot);
  }
}

// ---------------- angle-only bond (F_dist terms folded into towers_kernel) ----------------
__global__ __launch_bounds__(256)
void angle_bond_kernel(const float* __restrict__ Fa, const float* __restrict__ BC,
                       float* __restrict__ out)
{
  __shared__ float sa[256 * NANG];
  __shared__ float sred[4];
  const int tid = threadIdx.x;
  const size_t b0 = (size_t)blockIdx.x * 256;
  for (int k = tid; k < 256 * NANG; k += 256) sa[k] = Fa[b0 * NANG + k];
  __syncthreads();
  const float* a = &sa[tid * NANG];
  float bond = 0.f;
  #pragma unroll
  for (int j = 0; j < 7; ++j) { float t = a[j] - BC[16 + 9 + j]; bond += BC[9 + j] * t * t; }
  float u = 0.5f * bond;
  #pragma unroll
  for (int off = 32; off >= 1; off >>= 1) u += __shfl_xor(u, off, 64);
  if ((tid & 63) == 0) sred[tid >> 6] = u;
  __syncthreads();
  if (tid == 0) atomicAdd(out, sred[0] + sred[1] + sred[2] + sred[3]);
}

extern "C" void kernel_launch(void* const* d_in, const int* in_sizes, int n_in,
                              void* d_out, int out_size, void* d_ws, size_t ws_size,
                              hipStream_t stream)
{
  (void)in_sizes; (void)n_in; (void)d_ws; (void)ws_size; (void)out_size;
  const float* F_dist  = (const float*)d_in[0];
  const float* F_cos   = (const float*)d_in[1];
  const float* F_sin   = (const float*)d_in[2];
  const float* F_angle = (const float*)d_in[3];
  const float* Zd      = (const float*)d_in[4];
  const float* Zc      = (const float*)d_in[5];
  const float* Zs      = (const float*)d_in[6];
  const float* BC      = (const float*)d_in[7];
  const float* W1d     = (const float*)d_in[8];
  const float* b1d     = (const float*)d_in[9];
  const float* Whd     = (const float*)d_in[10];
  const float* bhd     = (const float*)d_in[11];
  const float* Wod     = (const float*)d_in[12];
  const float* bod     = (const float*)d_in[13];
  const float* W1a     = (const float*)d_in[14];
  const float* b1a     = (const float*)d_in[15];
  const float* Wha     = (const float*)d_in[16];
  const float* bha     = (const float*)d_in[17];
  const float* Woa     = (const float*)d_in[18];
  const float* boa     = (const float*)d_in[19];
  float* out = (float*)d_out;

  hipMemsetAsync(d_out, 0, sizeof(float), stream);
  angle_bond_kernel<<<dim3(262144 / 256), dim3(256), 0, stream>>>(F_angle, BC, out);
  towers_kernel<<<dim3(NTOW * NSLICE), dim3(512), 0, stream>>>(
      F_dist, F_cos, F_sin, Zd, Zc, Zs, BC,
      W1d, b1d, Whd, bhd, Wod, bod,
      W1a, b1a, Wha, bha, Woa, boa, out);
}